// Round 8
// baseline (225.947 us; speedup 1.0000x reference)
//
#include <hip/hip_runtime.h>
#include <hip/hip_bf16.h>
#include <math.h>

#define NROWS 1024
#define DIMS  1024
#define NHEAD 16
#define DHEAD 64

typedef float  f32x4  __attribute__((ext_vector_type(4)));
typedef float  f32x16 __attribute__((ext_vector_type(16)));
typedef short  s16x8  __attribute__((ext_vector_type(8)));
typedef unsigned int u32x4 __attribute__((ext_vector_type(4)));
typedef unsigned int u32x2 __attribute__((ext_vector_type(2)));

__device__ __forceinline__ unsigned short bf16u(float f) {
    return __builtin_bit_cast(unsigned short, __float2bfloat16(f));
}
__device__ __forceinline__ float bf16_f(unsigned short h) {
    unsigned int u = ((unsigned int)h) << 16;
    return __builtin_bit_cast(float, u);
}
__device__ __forceinline__ unsigned pk2(float a, float b) {
    return (unsigned)bf16u(a) | ((unsigned)bf16u(b) << 16);
}
__device__ __forceinline__ f32x4 mfma16(s16x8 a, s16x8 b, f32x4 c) {
    return __builtin_amdgcn_mfma_f32_16x16x32_bf16(a, b, c, 0, 0, 0);
}
__device__ __forceinline__ f32x16 mfma32(s16x8 a, s16x8 b, f32x16 c) {
    return __builtin_amdgcn_mfma_f32_32x32x16_bf16(a, b, c, 0, 0, 0);
}
// async global->LDS, 16B/lane: LDS dest = uniform base + lane*16
__device__ __forceinline__ void gld16(const void* g, void* l) {
    __builtin_amdgcn_global_load_lds(
        (const __attribute__((address_space(1))) unsigned int*)g,
        (__attribute__((address_space(3))) unsigned int*)l, 16, 0, 0);
}
// byte offset into a [rows][64] bf16 LDS tile (128B rows), 16B-slot XOR swizzle
__device__ __forceinline__ int swzB(int row, int byteCol16) {
    return row * 128 + (((byteCol16 >> 4) ^ (row & 7)) << 4);
}

// ---------------------------------------------------------------------------
// prep_all: z<8  -> Y fp32 tile (b=z): Ybf (row-major bf16) + Yt (per-head
//                   transposed bf16)
//           z==8 -> W1[k][n] -> Th[n][k] bf16 transpose.
// grid (16, 16, 9), 256 threads.
// ---------------------------------------------------------------------------
__global__ __launch_bounds__(256)
void prep_all(const float* __restrict__ Y, unsigned short* __restrict__ Ybf,
              unsigned short* __restrict__ Yt, const float* __restrict__ W1,
              unsigned short* __restrict__ Th)
{
    __shared__ float tile[64][65];
    const int t = threadIdx.x;
    const int b = blockIdx.z;

    if (b < 8) {
        const int m0 = blockIdx.x * 64;
        const int h  = blockIdx.y;
        const float* src = Y + ((size_t)(b * NROWS + m0)) * DIMS + h * DHEAD;
#pragma unroll
        for (int i = 0; i < 4; ++i) {
            int f  = t + 256 * i;
            int r  = f >> 4;
            int c4 = f & 15;
            float4 v = *(const float4*)(src + (size_t)r * DIMS + c4 * 4);
            tile[r][c4 * 4 + 0] = v.x; tile[r][c4 * 4 + 1] = v.y;
            tile[r][c4 * 4 + 2] = v.z; tile[r][c4 * 4 + 3] = v.w;
            u32x2 pk; pk[0] = pk2(v.x, v.y); pk[1] = pk2(v.z, v.w);
            *(u32x2*)(Ybf + (size_t)(b * NROWS + m0 + r) * DIMS + h * DHEAD + c4 * 4) = pk;
        }
        __syncthreads();
        const int d  = t >> 2;
        const int j0 = (t & 3) * 16;
        u32x4 o0, o1;
#pragma unroll
        for (int k = 0; k < 4; ++k) {
            o0[k] = pk2(tile[j0 + 2 * k][d],     tile[j0 + 2 * k + 1][d]);
            o1[k] = pk2(tile[j0 + 8 + 2 * k][d], tile[j0 + 9 + 2 * k][d]);
        }
        size_t off = ((size_t)((b * NHEAD + h) * DHEAD + d)) * NROWS + m0 + j0;
        *(u32x4*)(Yt + off)     = o0;
        *(u32x4*)(Yt + off + 8) = o1;
    } else {
        const int bx = blockIdx.x;   // k tile
        const int by = blockIdx.y;   // n tile
#pragma unroll
        for (int i = 0; i < 4; ++i) {
            int f  = t + 256 * i;
            int kk = f >> 4;
            int c4 = f & 15;
            float4 v = *(const float4*)(W1 + (size_t)(bx * 64 + kk) * DIMS + by * 64 + c4 * 4);
            tile[kk][c4 * 4 + 0] = v.x; tile[kk][c4 * 4 + 1] = v.y;
            tile[kk][c4 * 4 + 2] = v.z; tile[kk][c4 * 4 + 3] = v.w;
        }
        __syncthreads();
        const int nn = t >> 2;
        const int k0 = (t & 3) * 16;
#pragma unroll
        for (int c = 0; c < 2; ++c) {
            u32x4 ph;
#pragma unroll
            for (int e2 = 0; e2 < 4; ++e2)
                ph[e2] = pk2(tile[k0 + c * 8 + e2 * 2][nn], tile[k0 + c * 8 + e2 * 2 + 1][nn]);
            *(u32x4*)(Th + (size_t)(by * 64 + nn) * DIMS + bx * 64 + k0 + c * 8) = ph;
        }
    }
}

// ---------------------------------------------------------------------------
// attn: flash attention, 32x32x16 MFMA, swapped S^T=K*Q^T, P in registers,
// NO-max softmax via exp2 (Q pre-scaled by log2e/32). Grid 1024, XCD swizzle.
// ---------------------------------------------------------------------------
__global__ __launch_bounds__(256, 4)
void attn_mfma(const float* __restrict__ X, const unsigned short* __restrict__ Ybf,
               const unsigned short* __restrict__ Yt, float* __restrict__ Hpre)
{
    __shared__ __align__(16) char smem[34816];

    const int t    = threadIdx.x;
    const int lane = t & 63;
    const int w    = t >> 6;
    const int l31  = lane & 31;
    const int hi   = lane >> 5;

    const int bid = blockIdx.x;
    const int sid = (bid & 7) * 128 + (bid >> 3);
    const int q0  = (sid & 7) * 128;
    const int h   = (sid >> 3) & 15;
    const int b   = sid >> 7;

    const unsigned short* Ksrc = Ybf + ((size_t)b * NROWS) * DIMS + h * DHEAD;
    const unsigned short* Vsrc = Yt + ((size_t)((b * NHEAD + h) * DHEAD)) * NROWS;
    const float SCALE2 = 0.0450842200277981f;   // log2(e)/32: P = exp2(S*log2e)

    s16x8 qf[4];
    {
        const float* qp = X + ((size_t)(b * NROWS + q0 + w * 32 + l31)) * DIMS + h * DHEAD;
#pragma unroll
        for (int st = 0; st < 4; ++st) {
            float4 a0 = *(const float4*)(qp + st * 16 + hi * 8);
            float4 a1 = *(const float4*)(qp + st * 16 + hi * 8 + 4);
            s16x8 q;
            q[0] = (short)bf16u(a0.x * SCALE2); q[1] = (short)bf16u(a0.y * SCALE2);
            q[2] = (short)bf16u(a0.z * SCALE2); q[3] = (short)bf16u(a0.w * SCALE2);
            q[4] = (short)bf16u(a1.x * SCALE2); q[5] = (short)bf16u(a1.y * SCALE2);
            q[6] = (short)bf16u(a1.z * SCALE2); q[7] = (short)bf16u(a1.w * SCALE2);
            qf[st] = q;
        }
    }

    float l_i = 0.f;
    f32x16 acc[2];
#pragma unroll
    for (int df = 0; df < 2; ++df)
#pragma unroll
        for (int r = 0; r < 16; ++r) acc[df][r] = 0.f;

    auto stage = [&](int kt, int sel) {
        const int kvb = kt * 64;
        char* kbase = smem + sel * 16384;
        char* vbase = kbase + 8192;
#pragma unroll
        for (int c = 0; c < 2; ++c) {
            int idx  = (w * 2 + c) * 64 + lane;
            int row  = idx >> 3;
            int slot = idx & 7;
            int ss   = slot ^ (row & 7);
            gld16(Ksrc + (size_t)(kvb + row) * DIMS + ss * 8, kbase + (w * 2 + c) * 1024);
            gld16(Vsrc + (size_t)row * NROWS + kvb + ss * 8,  vbase + (w * 2 + c) * 1024);
        }
    };

    stage(0, 0);
    __syncthreads();
    int buf = 0;

    for (int kt = 0; kt < 16; ++kt) {
        if (kt + 1 < 16) stage(kt + 1, buf ^ 1);
        char* kbase = smem + buf * 16384;
        char* vbase = kbase + 8192;

        f32x16 sA[2];
#pragma unroll
        for (int f = 0; f < 2; ++f)
#pragma unroll
            for (int r = 0; r < 16; ++r) sA[f][r] = 0.f;
        __builtin_amdgcn_s_setprio(1);
#pragma unroll
        for (int st = 0; st < 4; ++st)
#pragma unroll
            for (int f = 0; f < 2; ++f) {
                int row = f * 32 + l31;
                s16x8 kf = __builtin_bit_cast(s16x8,
                    *(const u32x4*)(kbase + swzB(row, st * 32 + hi * 16)));
                sA[f] = mfma32(kf, qf[st], sA[f]);
            }
        __builtin_amdgcn_s_setprio(0);

#pragma unroll
        for (int f = 0; f < 2; ++f)
#pragma unroll
            for (int r = 0; r < 16; ++r) {
                float p = exp2f(sA[f][r]);
                sA[f][r] = p;
                l_i += p;
            }

        unsigned P2[2][4][2];
#pragma unroll
        for (int f = 0; f < 2; ++f)
#pragma unroll
            for (int r2 = 0; r2 < 4; ++r2) {
                P2[f][r2][0] = pk2(sA[f][r2 * 4 + 0], sA[f][r2 * 4 + 1]);
                P2[f][r2][1] = pk2(sA[f][r2 * 4 + 2], sA[f][r2 * 4 + 3]);
            }

#pragma unroll
        for (int s = 0; s < 4; ++s) {
            const int f  = s >> 1;
            const int s1 = s & 1;
            unsigned own0 = hi ? P2[f][2 * s1 + 1][0] : P2[f][2 * s1][0];
            unsigned own1 = hi ? P2[f][2 * s1 + 1][1] : P2[f][2 * s1][1];
            unsigned opp0 = hi ? P2[f][2 * s1][0] : P2[f][2 * s1 + 1][0];
            unsigned opp1 = hi ? P2[f][2 * s1][1] : P2[f][2 * s1 + 1][1];
            unsigned ex0 = __shfl_xor(opp0, 32);
            unsigned ex1 = __shfl_xor(opp1, 32);
            u32x4 bfv;
            bfv[0] = hi ? ex0 : own0;
            bfv[1] = hi ? ex1 : own1;
            bfv[2] = hi ? own0 : ex0;
            bfv[3] = hi ? own1 : ex1;
            s16x8 pfrag = __builtin_bit_cast(s16x8, bfv);
            __builtin_amdgcn_s_setprio(1);
#pragma unroll
            for (int df = 0; df < 2; ++df) {
                int row = df * 32 + l31;
                s16x8 vf = __builtin_bit_cast(s16x8,
                    *(const u32x4*)(vbase + swzB(row, s * 32 + hi * 16)));
                acc[df] = mfma32(vf, pfrag, acc[df]);
            }
            __builtin_amdgcn_s_setprio(0);
        }

        __syncthreads();
        buf ^= 1;
    }

    l_i += __shfl_xor(l_i, 32);
    float inv = 1.f / l_i;
    float* Ot = (float*)smem;              // [128][68]
    const int q = w * 32 + l31;
#pragma unroll
    for (int df = 0; df < 2; ++df)
#pragma unroll
        for (int r = 0; r < 16; ++r) {
            int d = df * 32 + (r & 3) + 8 * (r >> 2) + 4 * hi;
            Ot[q * 68 + d] = acc[df][r] * inv;
        }
    __syncthreads();
    const float* Xrow = X    + ((size_t)(b * NROWS + q0)) * DIMS + h * DHEAD;
    float*       Hrow = Hpre + ((size_t)(b * NROWS + q0)) * DIMS + h * DHEAD;
#pragma unroll
    for (int i = 0; i < 8; ++i) {
        int f  = t + 256 * i;
        int qr = f >> 4;
        int c4 = f & 15;
        float4 o = *(float4*)&Ot[qr * 68 + c4 * 4];
        float4 x = *(const float4*)(Xrow + (size_t)qr * DIMS + c4 * 4);
        o.x += x.x; o.y += x.y; o.z += x.z; o.w += x.w;
        *(float4*)(Hrow + (size_t)qr * DIMS + c4 * 4) = o;
    }
}

// ---------------------------------------------------------------------------
// ln_split: wave-per-row LayerNorm, bf16 OUTPUT ONLY (Hh). 4 rows/block.
// ---------------------------------------------------------------------------
__global__ __launch_bounds__(256)
void ln_split(const float* __restrict__ in, const float* __restrict__ gamma,
              const float* __restrict__ beta, unsigned short* __restrict__ Hh)
{
    const int row  = blockIdx.x * 4 + (threadIdx.x >> 6);
    const int lane = threadIdx.x & 63;
    const float* r = in + (size_t)row * DIMS;

    float4 v[4];
    float s = 0.f, ss = 0.f;
#pragma unroll
    for (int i = 0; i < 4; ++i) {
        v[i] = *(const float4*)(r + i * 256 + lane * 4);
        s  += v[i].x + v[i].y + v[i].z + v[i].w;
        ss += v[i].x * v[i].x + v[i].y * v[i].y + v[i].z * v[i].z + v[i].w * v[i].w;
    }
#pragma unroll
    for (int m = 1; m < 64; m <<= 1) {
        s  += __shfl_xor(s,  m);
        ss += __shfl_xor(ss, m);
    }
    const float mu  = s * (1.f / DIMS);
    const float var = ss * (1.f / DIMS) - mu * mu;
    const float inv = rsqrtf(var + 1e-5f);

#pragma unroll
    for (int i = 0; i < 4; ++i) {
        float4 g  = *(const float4*)(gamma + i * 256 + lane * 4);
        float4 be = *(const float4*)(beta  + i * 256 + lane * 4);
        float4 o;
        o.x = (v[i].x - mu) * inv * g.x + be.x;
        o.y = (v[i].y - mu) * inv * g.y + be.y;
        o.z = (v[i].z - mu) * inv * g.z + be.z;
        o.w = (v[i].w - mu) * inv * g.w + be.w;
        u32x2 pk; pk[0] = pk2(o.x, o.y); pk[1] = pk2(o.z, o.w);
        *(u32x2*)(Hh + (size_t)row * DIMS + i * 256 + lane * 4) = pk;
    }
}

// ---------------------------------------------------------------------------
// ln_kernel: wave-per-row final LayerNorm fp32 -> out. 4 rows/block.
// ---------------------------------------------------------------------------
__global__ __launch_bounds__(256)
void ln_kernel(const float* __restrict__ in, const float* __restrict__ gamma,
               const float* __restrict__ beta, float* __restrict__ out)
{
    const int row  = blockIdx.x * 4 + (threadIdx.x >> 6);
    const int lane = threadIdx.x & 63;
    const float* r = in + (size_t)row * DIMS;

    float4 v[4];
    float s = 0.f, ss = 0.f;
#pragma unroll
    for (int i = 0; i < 4; ++i) {
        v[i] = *(const float4*)(r + i * 256 + lane * 4);
        s  += v[i].x + v[i].y + v[i].z + v[i].w;
        ss += v[i].x * v[i].x + v[i].y * v[i].y + v[i].z * v[i].z + v[i].w * v[i].w;
    }
#pragma unroll
    for (int m = 1; m < 64; m <<= 1) {
        s  += __shfl_xor(s,  m);
        ss += __shfl_xor(ss, m);
    }
    const float mu  = s * (1.f / DIMS);
    const float var = ss * (1.f / DIMS) - mu * mu;
    const float inv = rsqrtf(var + 1e-5f);

#pragma unroll
    for (int i = 0; i < 4; ++i) {
        float4 g  = *(const float4*)(gamma + i * 256 + lane * 4);
        float4 be = *(const float4*)(beta  + i * 256 + lane * 4);
        float4 o;
        o.x = (v[i].x - mu) * inv * g.x + be.x;
        o.y = (v[i].y - mu) * inv * g.y + be.y;
        o.z = (v[i].z - mu) * inv * g.z + be.z;
        o.w = (v[i].w - mu) * inv * g.w + be.w;
        *(float4*)(out + (size_t)row * DIMS + i * 256 + lane * 4) = o;
    }
}

// ---------------------------------------------------------------------------
// ffn: Opre = Hn + relu(Hn @ W1 + b1).  128x128 tile, BK=64, 4 waves,
// double-buffered LDS (2x32KB) with prefetch-next (one barrier/iter).
// A = Hh (bf16), residual from Hh (L2-hot), output Opre fp32.
// grid 512 linear, XCD-chunked.
// ---------------------------------------------------------------------------
__global__ __launch_bounds__(256, 2)
void ffn_mfma(float* __restrict__ Opre, const unsigned short* __restrict__ Ah_g,
              const unsigned short* __restrict__ Th, const float* __restrict__ b1)
{
    __shared__ __align__(16) unsigned short Ah[2][128 * 64];   // 2x16KB
    __shared__ __align__(16) unsigned short Bh[2][128 * 64];   // 2x16KB

    const int t    = threadIdx.x;
    const int lane = t & 63;
    const int w    = t >> 6;
    const int l16  = lane & 15;
    const int lg   = lane >> 4;
    const int wm   = w >> 1;          // 0..1 (64 m-rows each)
    const int wn   = w & 1;           // 0..1 (64 n-cols each)

    const int bid = blockIdx.x;
    const int sid = (bid & 7) * 64 + (bid >> 3);   // XCD-chunked, 512 blocks
    const int n0  = (sid & 7) * 128;
    const int m0  = (sid >> 3) * 128;

    f32x4 acc[4][4];
#pragma unroll
    for (int i = 0; i < 4; ++i)
#pragma unroll
        for (int j = 0; j < 4; ++j) acc[i][j] = (f32x4){0.f, 0.f, 0.f, 0.f};

    auto stage = [&](int kt, int sel) {
#pragma unroll
        for (int c = 0; c < 4; ++c) {
            int idx = (w * 4 + c) * 64 + lane;     // 0..1023
            int row = idx >> 3;
            int ss  = (idx & 7) ^ (row & 7);
            gld16(Ah_g + (size_t)(m0 + row) * DIMS + kt * 64 + ss * 8,
                  (char*)Ah[sel] + (w * 4 + c) * 1024);
            gld16(Th + (size_t)(n0 + row) * DIMS + kt * 64 + ss * 8,
                  (char*)Bh[sel] + (w * 4 + c) * 1024);
        }
    };

    stage(0, 0);
    __syncthreads();
    int buf = 0;

    for (int kt = 0; kt < 16; ++kt) {
        if (kt + 1 < 16) stage(kt + 1, buf ^ 1);

#pragma unroll
        for (int kt2 = 0; kt2 < 2; ++kt2) {
            s16x8 af[4], bf[4];
#pragma unroll
            for (int mf = 0; mf < 4; ++mf) {
                int arow = wm * 64 + mf * 16 + l16;
                af[mf] = __builtin_bit_cast(s16x8,
                    *(const u32x4*)((const char*)Ah[buf] + swzB(arow, kt2 * 64 + lg * 16)));
            }
#pragma unroll
            for (int nf = 0; nf < 4; ++nf) {
                int brow = wn * 64 + nf * 16 + l16;
                bf[nf] = __builtin_bit_cast(s16x8,
                    *(const u32x4*)((const char*)Bh[buf] + swzB(brow, kt2 * 64 + lg * 16)));
            }
            __builtin_amdgcn_s_setprio(1);
#pragma unroll
            for (int mf = 0; mf < 4; ++mf)
#pragma unroll
                for (int nf = 0; nf < 4; ++nf)
                    acc[mf][nf] = mfma16(af[mf], bf[nf], acc[mf][nf]);
            __builtin_amdgcn_s_setprio(0);
        }

        __syncthreads();   // drains glds vmcnt + ds reads; next buffer ready
        buf ^= 1;
    }

    float bias[4];
#pragma unroll
    for (int nf = 0; nf < 4; ++nf) bias[nf] = b1[n0 + wn * 64 + nf * 16 + l16];

#pragma unroll
    for (int mf = 0; mf < 4; ++mf)
#pragma unroll
        for (int nf = 0; nf < 4; ++nf)
#pragma unroll
            for (int r = 0; r < 4; ++r) {
                int m = m0 + wm * 64 + mf * 16 + lg * 4 + r;
                int n = n0 + wn * 64 + nf * 16 + l16;
                size_t off = (size_t)m * DIMS + n;
                float v = fmaxf(acc[mf][nf][r] + bias[nf], 0.f);
                Opre[off] = bf16_f(Ah_g[off]) + v;   // residual from bf16 Hn (L2-hot)
            }
}

// ---------------------------------------------------------------------------
extern "C" void kernel_launch(void* const* d_in, const int* in_sizes, int n_in,
                              void* d_out, int out_size, void* d_ws, size_t ws_size,
                              hipStream_t stream)
{
    const float* X  = (const float*)d_in[0];
    const float* Y  = (const float*)d_in[1];
    const float* W1 = (const float*)d_in[2];
    const float* b1 = (const float*)d_in[3];
    const float* gh = (const float*)d_in[4];
    const float* bh = (const float*)d_in[5];
    const float* go = (const float*)d_in[6];
    const float* bo = (const float*)d_in[7];

    unsigned short* Ybf = (unsigned short*)d_out;                        // 16 MB
    unsigned short* Yt  = (unsigned short*)((char*)d_out + (16u << 20)); // 16 MB
    unsigned short* Hh  = (unsigned short*)d_out;                        // 16 MB (after attn)

    float*          R0 = (float*)d_ws;                                   // 32 MB
    unsigned short* Th = (unsigned short*)((char*)d_ws + (32u << 20));    // 2 MB

    // prep: Ybf/Yt (z<8) + W1^T (z==8)
    prep_all<<<dim3(16, 16, 9), 256, 0, stream>>>(Y, Ybf, Yt, W1, Th);

    // Hpre = X + attn(X, Y) -> R0
    attn_mfma<<<dim3(1024), 256, 0, stream>>>(X, Ybf, Yt, R0);

    // Hn = LN(Hpre) -> Hh bf16 only (Ybf/Yt dead)
    ln_split<<<dim3(2048), 256, 0, stream>>>(R0, gh, bh, Hh);

    // Opre = bf16(Hn) + relu(Hn @ W1 + b1) -> R0 (write-only)
    ffn_mfma<<<dim3(512), 256, 0, stream>>>(R0, Hh, Th, b1);

    // out = LN(Opre)
    ln_kernel<<<dim3(2048), 256, 0, stream>>>(R0, go, bo, (float*)d_out);
}